// Round 4
// baseline (845.985 us; speedup 1.0000x reference)
//
#include <hip/hip_runtime.h>
#include <cstddef>

typedef __attribute__((ext_vector_type(4))) float f4;

#define GK 512   // reduction dim D
#define GN 1024  // vocab V

// Fully fused, ZERO-workspace kernel (ws poison is unconditional; using ws buys
// nothing, avoiding it costs nothing — but fusion avoids the EC round-trip).
//   out[bt][u][v] = E[bt][v] + D[b,u][v],  E = enc@W^T + bias, D = dec@W^T
// Per block: 128x128x512 GEMM ([enc 64 rows ; dec 64 rows] @ Wv^T), E/D parked
// in LDS, then broadcast-add write of a disjoint 2.1 MB output slab.
// grid (32,8), block 512.
// Round-4 changes vs round-3:
//   1. double-buffered K-loop staging -> ONE barrier per K-tile (18 vs 33).
//   2. write phase: d4 hoisted to registers (thread-invariant u rows) ->
//      LDS reads cut 5x, stores decoupled from LDS latency.
__global__ __launch_bounds__(512) void joint_fused(
    const float* __restrict__ enc,   // [2048][512]
    const float* __restrict__ dec,   // [512][512] (8 batches x 64 rows)
    const float* __restrict__ W,     // [1024][512]
    const float* __restrict__ bias,  // [1024]
    float* __restrict__ out)         // [2048*64][1024]
{
    __shared__ float smem[16384];    // 64 KB
    // K-loop double buffers: buf p at smem + p*8192 (As 4096 | Ws 4096)
    // post-GEMM park:  Es = smem[0..8192)  (aliases buf0, barrier-protected)
    //                  Ds = smem[8192..16384) (aliases buf1, barrier-protected)
    float* Es = smem;
    float* Ds = smem + 8192;

    const int tid = threadIdx.x;
    const int bt0 = blockIdx.x * 64;      // 64 enc rows per block (same batch)
    const int b   = blockIdx.x >> 2;      // batch id
    const int v0  = blockIdx.y * 128;     // v-tile

    const float* __restrict__ Ae = enc + (size_t)bt0 * GK;
    const float* __restrict__ Ad = dec + (size_t)b * 64 * GK;
    const float* __restrict__ Wv = W + (size_t)v0 * GK;

    const int tx = tid & 15;   // 16 col groups x 8 cols
    const int ty = tid >> 4;   // 32 row groups x 4 rows -> 128 rows
    const int ar = tid >> 3;   // 0..63 (staging row)
    const int ak = tid & 7;    // k-quad 0..7

    float acc[4][8];
#pragma unroll
    for (int i = 0; i < 4; ++i)
#pragma unroll
        for (int j = 0; j < 8; ++j) acc[i][j] = 0.f;

    f4 rae, rad, rw0, rw1;
    {
        const float* pe = Ae + (size_t)ar * GK + (ak << 2);
        const float* pd = Ad + (size_t)ar * GK + (ak << 2);
        const float* pw = Wv + (size_t)ar * GK + (ak << 2);
        rae = *(const f4*)pe;
        rad = *(const f4*)pd;
        rw0 = *(const f4*)pw;
        rw1 = *(const f4*)(pw + (size_t)64 * GK);
    }

    const int qoff = ((ak ^ (ar >> 3)) & 7) << 2;  // XOR-quad swizzle (both halves equal)

    // ---- K-loop: one barrier per tile, double-buffered staging ----
#define KSTEP(AS, WS, T)                                                        \
    {                                                                           \
        float* As = (AS);                                                       \
        float* Ws = (WS);                                                       \
        *(f4*)(&As[ar * 32 + qoff])        = rae;                               \
        *(f4*)(&As[(64 + ar) * 32 + qoff]) = rad;                               \
        *(f4*)(&Ws[ar * 32 + qoff])        = rw0;                               \
        *(f4*)(&Ws[(64 + ar) * 32 + qoff]) = rw1;                               \
        __syncthreads();                                                        \
        if ((T) + 1 < 16) {                                                     \
            const int kn = ((T) + 1) << 5;                                      \
            const float* pe = Ae + (size_t)ar * GK + kn + (ak << 2);            \
            const float* pd = Ad + (size_t)ar * GK + kn + (ak << 2);            \
            const float* pw = Wv + (size_t)ar * GK + kn + (ak << 2);            \
            rae = *(const f4*)pe;                                               \
            rad = *(const f4*)pd;                                               \
            rw0 = *(const f4*)pw;                                               \
            rw1 = *(const f4*)(pw + (size_t)64 * GK);                           \
        }                                                                       \
        _Pragma("unroll")                                                       \
        for (int kq = 0; kq < 8; ++kq) {                                        \
            f4 a4[4], b4[8];                                                    \
            const int pb = ((kq ^ tx) & 7) << 2;                                \
            _Pragma("unroll")                                                   \
            for (int i = 0; i < 4; ++i) {                                       \
                const int m = ty * 4 + i;                                       \
                a4[i] = *(const f4*)(&As[m * 32 + (((kq ^ (m >> 3)) & 7) << 2)]);\
            }                                                                   \
            _Pragma("unroll")                                                   \
            for (int j = 0; j < 8; ++j)                                         \
                b4[j] = *(const f4*)(&Ws[(tx * 8 + j) * 32 + pb]);              \
            _Pragma("unroll")                                                   \
            for (int i = 0; i < 4; ++i)                                         \
                _Pragma("unroll")                                               \
                for (int j = 0; j < 8; ++j) {                                   \
                    acc[i][j] = fmaf(a4[i].x, b4[j].x, acc[i][j]);              \
                    acc[i][j] = fmaf(a4[i].y, b4[j].y, acc[i][j]);              \
                    acc[i][j] = fmaf(a4[i].z, b4[j].z, acc[i][j]);              \
                    acc[i][j] = fmaf(a4[i].w, b4[j].w, acc[i][j]);              \
                }                                                               \
        }                                                                       \
    }

#pragma unroll 1
    for (int t = 0; t < 16; t += 2) {
        KSTEP(smem,        smem + 4096,  t)       // buffer 0
        KSTEP(smem + 8192, smem + 12288, t + 1)   // buffer 1
    }
#undef KSTEP

    // all waves done computing (last reads were from buf1) before park clobbers it
    __syncthreads();

    // ---- park C in LDS: rows <64 -> Es (+bias), rows >=64 -> Ds ----
    {
        const bool isE = (ty < 16);
        f4 bi0 = {0.f, 0.f, 0.f, 0.f}, bi1 = {0.f, 0.f, 0.f, 0.f};
        if (isE) {  // bias exactly once, on the E part
            bi0 = *(const f4*)(bias + v0 + tx * 8);
            bi1 = *(const f4*)(bias + v0 + tx * 8 + 4);
        }
        float* Cs = isE ? Es : Ds;
        const int mloc = (ty & 15) * 4;
#pragma unroll
        for (int i = 0; i < 4; ++i) {
            f4 c0 = {acc[i][0] + bi0.x, acc[i][1] + bi0.y,
                     acc[i][2] + bi0.z, acc[i][3] + bi0.w};
            f4 c1 = {acc[i][4] + bi1.x, acc[i][5] + bi1.y,
                     acc[i][6] + bi1.z, acc[i][7] + bi1.w};
            *(f4*)(&Cs[(mloc + i) * 128 + tx * 8])     = c0;
            *(f4*)(&Cs[(mloc + i) * 128 + tx * 8 + 4]) = c1;
        }
    }
    __syncthreads();

    // ---- broadcast-add write: out[(bt0+g)*64 + u][v0 + 4*v4 ..] = E[g] + D[u] ----
    // u = s*16 + rlane is THREAD-INVARIANT -> d4[s] hoisted to registers once.
    {
        const int v4 = tid & 31;          // f4 column within the 128-wide v-tile
        const int rlane = tid >> 5;       // 0..15
        const f4* Es4 = (const f4*)Es;
        const f4* Ds4 = (const f4*)Ds;

        f4 d4[4];
#pragma unroll
        for (int s = 0; s < 4; ++s)
            d4[s] = Ds4[(s * 16 + rlane) * 32 + v4];

        float* obase = out + (size_t)bt0 * 64 * GN + v0 + 4 * v4;

#pragma unroll 2
        for (int g = 0; g < 64; ++g) {
            const f4 e4 = Es4[g * 32 + v4];
            float* orow = obase + (size_t)g * 64 * GN;
#pragma unroll
            for (int s = 0; s < 4; ++s) {
                const int u = s * 16 + rlane;
                *(f4*)(orow + (size_t)u * GN) = e4 + d4[s];
            }
        }
    }
}

extern "C" void kernel_launch(void* const* d_in, const int* in_sizes, int n_in,
                              void* d_out, int out_size, void* d_ws, size_t ws_size,
                              hipStream_t stream) {
    const float* enc  = (const float*)d_in[0];  // 8*256*512
    const float* dec  = (const float*)d_in[1];  // 8*64*512
    const float* W    = (const float*)d_in[2];  // 1024*512
    const float* bias = (const float*)d_in[3];  // 1024
    float* out = (float*)d_out;                 // 8*256*64*1024

    (void)d_ws; (void)ws_size;                  // workspace deliberately unused

    joint_fused<<<dim3(32, 8), dim3(512), 0, stream>>>(enc, dec, W, bias, out);
}